// Round 1
// baseline (182.004 us; speedup 1.0000x reference)
//
#include <hip/hip_runtime.h>
#include <hip/hip_bf16.h>
#include <math.h>
#include <stdint.h>

// Shapes: B=64, T=256, R=49, H=1024
// out = [c_t (B*T*H fp32)] ++ [alpha (B*T*R fp32)]
// ws  = [cv fp32 3136x49][cg fp32 16384x49][vT bf16 64x1024x64 swizzled] (~12.2 MB)
//
// Round 1: fused zsoftmax+PV. alpha never leaves LDS (as MFMA A operand);
// a16 intermediate (2MB w + 2MB r) and the third dispatch are gone.

typedef __attribute__((ext_vector_type(8))) short bf16x8;
typedef __attribute__((ext_vector_type(4))) float floatx4;

static __device__ __forceinline__ bf16x8 pack8(float4 a, float4 b) {
    union { __hip_bfloat162 h[4]; bf16x8 v; } u;
    u.h[0] = __float22bfloat162_rn(make_float2(a.x, a.y));
    u.h[1] = __float22bfloat162_rn(make_float2(a.z, a.w));
    u.h[2] = __float22bfloat162_rn(make_float2(b.x, b.y));
    u.h[3] = __float22bfloat162_rn(make_float2(b.z, b.w));
    return u.v;
}

static __device__ __forceinline__ unsigned short f2bf_bits(float f) {
    union { __hip_bfloat16 h; unsigned short u; } c;
    c.h = __float2bfloat16(f);
    return c.u;
}

// Blocks 0..97: cv = V.Wv^T (M-tile 32); 98..609: cg = h_t.Wg^T;
// 610..1121: transpose V -> vT[b][h][r(pad 64)] bf16, octet-swizzled rows.
__global__ __launch_bounds__(256) void gemm_mfma_tr(const float* __restrict__ Av,
                                                    const float* __restrict__ Ag,
                                                    const float* __restrict__ Wv,
                                                    const float* __restrict__ Wg,
                                                    float* __restrict__ Cv,
                                                    float* __restrict__ Cg,
                                                    unsigned short* __restrict__ vT) {
    __shared__ __align__(16) char smem[49 * 132 * 4];  // 25872 B, union
    const int bid = blockIdx.x;
    const int tid = threadIdx.x;

    if (bid >= 610) {
        // ---- V transpose: one (b, 128-h slice) per block ----
        float* Ts = (float*)smem;  // [49][132]
        const int tb = bid - 610;
        const int b = tb >> 3;
        const int h0 = (tb & 7) * 128;
        for (int i = tid; i < 49 * 32; i += 256) {
            const int r = i >> 5, hq = i & 31;
            *(float4*)(Ts + r * 132 + hq * 4) =
                *(const float4*)(Av + ((size_t)b * 49 + r) * 1024 + h0 + hq * 4);
        }
        __syncthreads();
        const int h = tid & 127;
        const int half = tid >> 7;  // 0: r 0..31 (octets 0..3), 1: r 32..63 (4..7)
        float f[32];
#pragma unroll
        for (int j = 0; j < 32; ++j) {
            const int r = half * 32 + j;
            f[j] = (r < 49) ? Ts[r * 132 + h] : 0.f;
        }
        const size_t rowbase = ((size_t)b * 1024 + h0 + h) * 64;
#pragma unroll
        for (int o2 = 0; o2 < 4; ++o2) {
            const int o = half * 4 + o2;
            bf16x8 v = pack8(make_float4(f[o2*8+0], f[o2*8+1], f[o2*8+2], f[o2*8+3]),
                             make_float4(f[o2*8+4], f[o2*8+5], f[o2*8+6], f[o2*8+7]));
            *(bf16x8*)(vT + rowbase + (size_t)((o ^ (h & 7)) * 8)) = v;
        }
        return;
    }

    // ---- GEMM C[m][n] = sum_k A[m][k]*W[n][k], K=1024, N=49->64 ----
    short* As = (short*)smem;           // [32][64]
    short* Ws = (short*)(smem + 4096);  // [64][64]
    const float* A; const float* W; float* C; int m0;
    if (bid < 98) { A = Av; W = Wv; C = Cv; m0 = bid * 32; }
    else          { A = Ag; W = Wg; C = Cg; m0 = (bid - 98) * 32; }

    const int wave = tid >> 6, lane = tid & 63;
    const int quad = lane >> 4, l16 = lane & 15;
    const int mb = (wave & 1) * 16;
    const int nb = (wave >> 1) * 32;

    floatx4 acc[2] = {};

    const int arow = tid >> 3, ag = tid & 7;
    const int wrow = tid >> 2, wq = tid & 3;
    const float* aptr = A + (size_t)(m0 + arow) * 1024 + ag * 8;
    const bool wvalid = wrow < 49;
    const float* wptr = W + (size_t)wrow * 1024 + wq * 16;

    float4 a0 = *(const float4*)(aptr);
    float4 a1 = *(const float4*)(aptr + 4);
    float4 w0 = make_float4(0.f,0.f,0.f,0.f), w1 = w0, w2 = w0, w3 = w0;
    if (wvalid) {
        w0 = *(const float4*)(wptr);
        w1 = *(const float4*)(wptr + 4);
        w2 = *(const float4*)(wptr + 8);
        w3 = *(const float4*)(wptr + 12);
    }

    for (int kc = 0; kc < 1024; kc += 64) {
        __syncthreads();
        *(bf16x8*)(As + arow * 64 + (ag ^ (arow & 7)) * 8) = pack8(a0, a1);
        *(bf16x8*)(Ws + wrow * 64 + ((wq * 2) ^ (wrow & 7)) * 8) = pack8(w0, w1);
        *(bf16x8*)(Ws + wrow * 64 + ((wq * 2 + 1) ^ (wrow & 7)) * 8) = pack8(w2, w3);
        __syncthreads();
        if (kc < 960) {  // prefetch next tile; latency hides under MFMA below
            a0 = *(const float4*)(aptr + kc + 64);
            a1 = *(const float4*)(aptr + kc + 68);
            if (wvalid) {
                w0 = *(const float4*)(wptr + kc + 64);
                w1 = *(const float4*)(wptr + kc + 68);
                w2 = *(const float4*)(wptr + kc + 72);
                w3 = *(const float4*)(wptr + kc + 76);
            }
        }
#pragma unroll
        for (int s = 0; s < 2; ++s) {
            const int am = mb + l16;
            bf16x8 af = *(const bf16x8*)(As + am * 64 + (((s << 2) + quad) ^ (am & 7)) * 8);
#pragma unroll
            for (int nt = 0; nt < 2; ++nt) {
                const int wn = nb + nt * 16 + l16;
                bf16x8 bf = *(const bf16x8*)(Ws + wn * 64 + (((s << 2) + quad) ^ (wn & 7)) * 8);
                acc[nt] = __builtin_amdgcn_mfma_f32_16x16x32_bf16(af, bf, acc[nt], 0, 0, 0);
            }
        }
    }

#pragma unroll
    for (int nt = 0; nt < 2; ++nt) {
        const int n = nb + nt * 16 + l16;
        if (n < 49) {
#pragma unroll
            for (int r = 0; r < 4; ++r) {
                const int m = m0 + mb + quad * 4 + r;
                C[(size_t)m * 49 + n] = acc[nt][r];
            }
        }
    }
}

// Fused: z[b,t,r] = sum_k tanh(cv[b,r,k]+cg[b,t,k])*Wh[k]; alpha=softmax_r(z);
// then c_t[b,t,h] = sum_r alpha*V via bf16 MFMA, alpha staying in LDS.
// Block = (b, 32-row t-tile). grid = 64*8 = 512.
__global__ __launch_bounds__(256) void zsoftmax_ct(const float* __restrict__ cv,
                                                   const float* __restrict__ cg,
                                                   const float* __restrict__ Wh,
                                                   const unsigned short* __restrict__ vT,
                                                   float* __restrict__ alpha,
                                                   float* __restrict__ C) {
    const int b = blockIdx.x >> 3;
    const int t0 = (blockIdx.x & 7) * 32;

    // [0,4096): Al (32x64 bf16, swizzled) — persists across phases.
    // [4096,...): phase1 {cvl 49x52 f32, cgl 32x52 f32, whl 52 f32} = 17056 B
    //             phase2 {Vl 128x64 bf16} = 16384 B (union)
    __shared__ __align__(16) char smem[4096 + 49 * 52 * 4 + 32 * 52 * 4 + 52 * 4];
    short* Al  = (short*)smem;
    float* cvl = (float*)(smem + 4096);
    float* cgl = cvl + 49 * 52;
    float* whl = cgl + 32 * 52;
    short* Vl  = (short*)(smem + 4096);

    const int tid = threadIdx.x;
    for (int i = tid; i < 49 * 49; i += 256) {
        int r = i / 49, k = i - r * 49;
        cvl[r * 52 + k] = cv[(size_t)b * 2401 + i];
    }
    for (int i = tid; i < 32 * 49; i += 256) {
        int t = i / 49, k = i - t * 49;
        cgl[t * 52 + k] = cg[((size_t)b * 256 + t0) * 49 + i];
    }
    if (tid < 52) whl[tid] = (tid < 49) ? Wh[tid] : 0.f;
    __syncthreads();

    const int wave = tid >> 6;
    const int lane = tid & 63;
    const int quad = lane >> 4, l16 = lane & 15;
    const float4* cvr = (const float4*)(cvl + lane * 52);
    const float4* wh4 = (const float4*)whl;

    // ---- phase 1: z + softmax; alpha -> global fp32 + LDS bf16 (swizzled) ----
    for (int i = 0; i < 8; ++i) {
        const int tl = wave * 8 + i;
        float z = -INFINITY;
        if (lane < 49) {
            const float4* cgr = (const float4*)(cgl + tl * 52);
            float s = 0.f;
#pragma unroll 4
            for (int kk = 0; kk < 12; ++kk) {
                float4 x = cvr[kk], g = cgr[kk], w = wh4[kk];
                float r0 = __builtin_amdgcn_rcpf(__expf(2.f * (x.x + g.x)) + 1.f);
                float r1 = __builtin_amdgcn_rcpf(__expf(2.f * (x.y + g.y)) + 1.f);
                float r2 = __builtin_amdgcn_rcpf(__expf(2.f * (x.z + g.z)) + 1.f);
                float r3 = __builtin_amdgcn_rcpf(__expf(2.f * (x.w + g.w)) + 1.f);
                s = fmaf(1.f - 2.f * r0, w.x, s);
                s = fmaf(1.f - 2.f * r1, w.y, s);
                s = fmaf(1.f - 2.f * r2, w.z, s);
                s = fmaf(1.f - 2.f * r3, w.w, s);
            }
            {
                float x = cvl[lane * 52 + 48] + cgl[tl * 52 + 48];
                float r0 = __builtin_amdgcn_rcpf(__expf(2.f * x) + 1.f);
                s = fmaf(1.f - 2.f * r0, whl[48], s);
            }
            z = s;
        }
        float m = z;
        for (int off = 32; off; off >>= 1) m = fmaxf(m, __shfl_xor(m, off));
        float p = (lane < 49) ? __expf(z - m) : 0.f;
        float sum = p;
        for (int off = 32; off; off >>= 1) sum += __shfl_xor(sum, off);
        const float val = p * __builtin_amdgcn_rcpf(sum);  // 0 for lane>=49

        const size_t grow = (size_t)b * 256 + t0 + tl;
        if (lane < 49) alpha[grow * 49 + lane] = val;
        const int pos = (((lane >> 3) ^ (tl & 7)) << 3) | (lane & 7);
        Al[tl * 64 + pos] = (short)f2bf_bits(val);
    }
    __syncthreads();  // phase boundary: cvl/cgl dead, Al valid

    // ---- phase 2: c_t = alpha @ V^T, looping 128-h chunks of vT ----
    const int tb = (wave & 1) * 16;   // t sub-tile within the 32 rows
    const int hb = (wave >> 1) * 64;  // h sub-tile within the 128 chunk

    bf16x8 af[2];
    {
        const int row = tb + l16;
#pragma unroll
        for (int kc = 0; kc < 2; ++kc)
            af[kc] = *(const bf16x8*)(Al + row * 64 + (((kc << 2) + quad) ^ (row & 7)) * 8);
    }

    const bf16x8* vsrc = (const bf16x8*)(vT + ((size_t)b * 1024) * 64);
    bf16x8 vreg[4];
#pragma unroll
    for (int p = 0; p < 4; ++p) vreg[p] = vsrc[tid + p * 256];

    for (int c = 0; c < 8; ++c) {
        bf16x8* dst = (bf16x8*)Vl;
#pragma unroll
        for (int p = 0; p < 4; ++p) dst[tid + p * 256] = vreg[p];
        __syncthreads();
        if (c < 7) {  // prefetch next chunk; hides under MFMA below
#pragma unroll
            for (int p = 0; p < 4; ++p) vreg[p] = vsrc[(size_t)(c + 1) * 1024 + tid + p * 256];
        }

        floatx4 acc[4] = {};
#pragma unroll
        for (int kc = 0; kc < 2; ++kc) {
#pragma unroll
            for (int ns = 0; ns < 4; ++ns) {
                const int row = hb + ns * 16 + l16;
                bf16x8 bf = *(const bf16x8*)(Vl + row * 64 + (((kc << 2) + quad) ^ (row & 7)) * 8);
                acc[ns] = __builtin_amdgcn_mfma_f32_16x16x32_bf16(af[kc], bf, acc[ns], 0, 0, 0);
            }
        }

        const int h0 = c << 7;
#pragma unroll
        for (int ns = 0; ns < 4; ++ns) {
            const int h = h0 + hb + ns * 16 + l16;
#pragma unroll
            for (int r = 0; r < 4; ++r) {
                const int tg = t0 + tb + quad * 4 + r;
                C[((size_t)b * 256 + tg) * 1024 + h] = acc[ns][r];
            }
        }
        __syncthreads();  // all reads of Vl done before next chunk's store
    }
}

extern "C" void kernel_launch(void* const* d_in, const int* in_sizes, int n_in,
                              void* d_out, int out_size, void* d_ws, size_t ws_size,
                              hipStream_t stream) {
    const float* V   = (const float*)d_in[0];
    const float* h_t = (const float*)d_in[1];
    const float* Wv  = (const float*)d_in[2];
    const float* Wg  = (const float*)d_in[3];
    const float* Wh  = (const float*)d_in[4];

    float* c_t   = (float*)d_out;
    float* alpha = (float*)d_out + 16777216;

    float* cv = (float*)d_ws;                                       // 153664 f
    float* cg = cv + 153664;                                        // 802816 f
    unsigned short* vT = (unsigned short*)((char*)d_ws + 3825920);  // 64*1024*64

    gemm_mfma_tr<<<610 + 512, 256, 0, stream>>>(V, h_t, Wv, Wg, cv, cg, vT);
    zsoftmax_ct<<<512, 256, 0, stream>>>(cv, cg, Wh, vT, alpha, c_t);
}

// Round 2
// 174.012 us; speedup vs baseline: 1.0459x; 1.0459x over previous
//
#include <hip/hip_runtime.h>
#include <hip/hip_bf16.h>
#include <math.h>
#include <stdint.h>

// Shapes: B=64, T=256, R=49, H=1024
// out = [c_t (B*T*H fp32)] ++ [alpha (B*T*R fp32)]
// ws  = [cv fp32 3136x49][cg fp32 16384x49][vT bf16 64x1024x64 swizzled] (~12.2 MB)
//
// Round 2: fused zsoftmax+PV, re-parallelized. Grid 1024 (t-tile 16, 4 blk/CU),
// phase 2 reads V fragments DIRECTLY from global vT (no LDS stage, no barriers),
// XCD-chunked block swizzle keeps each b's 128KB vT slice in one XCD's L2.

typedef __attribute__((ext_vector_type(8))) short bf16x8;
typedef __attribute__((ext_vector_type(4))) float floatx4;

static __device__ __forceinline__ bf16x8 pack8(float4 a, float4 b) {
    union { __hip_bfloat162 h[4]; bf16x8 v; } u;
    u.h[0] = __float22bfloat162_rn(make_float2(a.x, a.y));
    u.h[1] = __float22bfloat162_rn(make_float2(a.z, a.w));
    u.h[2] = __float22bfloat162_rn(make_float2(b.x, b.y));
    u.h[3] = __float22bfloat162_rn(make_float2(b.z, b.w));
    return u.v;
}

static __device__ __forceinline__ unsigned short f2bf_bits(float f) {
    union { __hip_bfloat16 h; unsigned short u; } c;
    c.h = __float2bfloat16(f);
    return c.u;
}

// Blocks 0..97: cv = V.Wv^T (M-tile 32); 98..609: cg = h_t.Wg^T;
// 610..1121: transpose V -> vT[b][h][r(pad 64)] bf16, octet-swizzled rows.
__global__ __launch_bounds__(256) void gemm_mfma_tr(const float* __restrict__ Av,
                                                    const float* __restrict__ Ag,
                                                    const float* __restrict__ Wv,
                                                    const float* __restrict__ Wg,
                                                    float* __restrict__ Cv,
                                                    float* __restrict__ Cg,
                                                    unsigned short* __restrict__ vT) {
    __shared__ __align__(16) char smem[49 * 132 * 4];  // 25872 B, union
    const int bid = blockIdx.x;
    const int tid = threadIdx.x;

    if (bid >= 610) {
        // ---- V transpose: one (b, 128-h slice) per block ----
        float* Ts = (float*)smem;  // [49][132]
        const int tb = bid - 610;
        const int b = tb >> 3;
        const int h0 = (tb & 7) * 128;
        for (int i = tid; i < 49 * 32; i += 256) {
            const int r = i >> 5, hq = i & 31;
            *(float4*)(Ts + r * 132 + hq * 4) =
                *(const float4*)(Av + ((size_t)b * 49 + r) * 1024 + h0 + hq * 4);
        }
        __syncthreads();
        const int h = tid & 127;
        const int half = tid >> 7;  // 0: r 0..31 (octets 0..3), 1: r 32..63 (4..7)
        float f[32];
#pragma unroll
        for (int j = 0; j < 32; ++j) {
            const int r = half * 32 + j;
            f[j] = (r < 49) ? Ts[r * 132 + h] : 0.f;
        }
        const size_t rowbase = ((size_t)b * 1024 + h0 + h) * 64;
#pragma unroll
        for (int o2 = 0; o2 < 4; ++o2) {
            const int o = half * 4 + o2;
            bf16x8 v = pack8(make_float4(f[o2*8+0], f[o2*8+1], f[o2*8+2], f[o2*8+3]),
                             make_float4(f[o2*8+4], f[o2*8+5], f[o2*8+6], f[o2*8+7]));
            *(bf16x8*)(vT + rowbase + (size_t)((o ^ (h & 7)) * 8)) = v;
        }
        return;
    }

    // ---- GEMM C[m][n] = sum_k A[m][k]*W[n][k], K=1024, N=49->64 ----
    short* As = (short*)smem;           // [32][64]
    short* Ws = (short*)(smem + 4096);  // [64][64]
    const float* A; const float* W; float* C; int m0;
    if (bid < 98) { A = Av; W = Wv; C = Cv; m0 = bid * 32; }
    else          { A = Ag; W = Wg; C = Cg; m0 = (bid - 98) * 32; }

    const int wave = tid >> 6, lane = tid & 63;
    const int quad = lane >> 4, l16 = lane & 15;
    const int mb = (wave & 1) * 16;
    const int nb = (wave >> 1) * 32;

    floatx4 acc[2] = {};

    const int arow = tid >> 3, ag = tid & 7;
    const int wrow = tid >> 2, wq = tid & 3;
    const float* aptr = A + (size_t)(m0 + arow) * 1024 + ag * 8;
    const bool wvalid = wrow < 49;
    const float* wptr = W + (size_t)wrow * 1024 + wq * 16;

    float4 a0 = *(const float4*)(aptr);
    float4 a1 = *(const float4*)(aptr + 4);
    float4 w0 = make_float4(0.f,0.f,0.f,0.f), w1 = w0, w2 = w0, w3 = w0;
    if (wvalid) {
        w0 = *(const float4*)(wptr);
        w1 = *(const float4*)(wptr + 4);
        w2 = *(const float4*)(wptr + 8);
        w3 = *(const float4*)(wptr + 12);
    }

    for (int kc = 0; kc < 1024; kc += 64) {
        __syncthreads();
        *(bf16x8*)(As + arow * 64 + (ag ^ (arow & 7)) * 8) = pack8(a0, a1);
        *(bf16x8*)(Ws + wrow * 64 + ((wq * 2) ^ (wrow & 7)) * 8) = pack8(w0, w1);
        *(bf16x8*)(Ws + wrow * 64 + ((wq * 2 + 1) ^ (wrow & 7)) * 8) = pack8(w2, w3);
        __syncthreads();
        if (kc < 960) {  // prefetch next tile; latency hides under MFMA below
            a0 = *(const float4*)(aptr + kc + 64);
            a1 = *(const float4*)(aptr + kc + 68);
            if (wvalid) {
                w0 = *(const float4*)(wptr + kc + 64);
                w1 = *(const float4*)(wptr + kc + 68);
                w2 = *(const float4*)(wptr + kc + 72);
                w3 = *(const float4*)(wptr + kc + 76);
            }
        }
#pragma unroll
        for (int s = 0; s < 2; ++s) {
            const int am = mb + l16;
            bf16x8 af = *(const bf16x8*)(As + am * 64 + (((s << 2) + quad) ^ (am & 7)) * 8);
#pragma unroll
            for (int nt = 0; nt < 2; ++nt) {
                const int wn = nb + nt * 16 + l16;
                bf16x8 bf = *(const bf16x8*)(Ws + wn * 64 + (((s << 2) + quad) ^ (wn & 7)) * 8);
                acc[nt] = __builtin_amdgcn_mfma_f32_16x16x32_bf16(af, bf, acc[nt], 0, 0, 0);
            }
        }
    }

#pragma unroll
    for (int nt = 0; nt < 2; ++nt) {
        const int n = nb + nt * 16 + l16;
        if (n < 49) {
#pragma unroll
            for (int r = 0; r < 4; ++r) {
                const int m = m0 + mb + quad * 4 + r;
                C[(size_t)m * 49 + n] = acc[nt][r];
            }
        }
    }
}

// Fused: z[b,t,r] = sum_k tanh(cv[b,r,k]+cg[b,t,k])*Wh[k]; alpha=softmax_r(z);
// c_t[b,t,h] = sum_r alpha*V via bf16 MFMA with B-fragments read straight
// from global vT (L2-resident). Block = (b, 16-row t-tile), grid 64*16=1024.
// XCD-chunked bid swizzle: 2 b's worth of blocks per XCD chunk of 128.
__global__ __launch_bounds__(256) void zsoftmax_ct(const float* __restrict__ cv,
                                                   const float* __restrict__ cg,
                                                   const float* __restrict__ Wh,
                                                   const unsigned short* __restrict__ vT,
                                                   float* __restrict__ alpha,
                                                   float* __restrict__ C) {
    // bijective: blocks [x*128, x*128+128) of orig-space land on XCD x
    const int bid = blockIdx.x;
    const int orig = (bid & 7) * 128 + (bid >> 3);
    const int b = orig >> 4;
    const int t0 = (orig & 15) * 16;

    __shared__ __align__(16) short Al[16 * 64];        // [t][r] bf16, swizzled
    __shared__ __align__(16) float cvl[49 * 52];
    __shared__ __align__(16) float cgl[16 * 52];
    __shared__ __align__(16) float whl[52];

    const int tid = threadIdx.x;
    for (int i = tid; i < 49 * 49; i += 256) {
        int r = i / 49, k = i - r * 49;
        cvl[r * 52 + k] = cv[(size_t)b * 2401 + i];
    }
    for (int i = tid; i < 16 * 49; i += 256) {
        int t = i / 49, k = i - t * 49;
        cgl[t * 52 + k] = cg[((size_t)b * 256 + t0) * 49 + i];
    }
    if (tid < 52) whl[tid] = (tid < 49) ? Wh[tid] : 0.f;
    __syncthreads();

    const int wave = tid >> 6;
    const int lane = tid & 63;
    const int quad = lane >> 4, l16 = lane & 15;
    const float4* cvr = (const float4*)(cvl + lane * 52);
    const float4* wh4 = (const float4*)whl;

    // ---- phase 1: z + softmax; alpha -> global fp32 + LDS bf16 (swizzled) ----
#pragma unroll
    for (int i = 0; i < 4; ++i) {
        const int tl = wave * 4 + i;
        float z = -INFINITY;
        if (lane < 49) {
            const float4* cgr = (const float4*)(cgl + tl * 52);
            float s = 0.f;
#pragma unroll 4
            for (int kk = 0; kk < 12; ++kk) {
                float4 x = cvr[kk], g = cgr[kk], w = wh4[kk];
                float r0 = __builtin_amdgcn_rcpf(__expf(2.f * (x.x + g.x)) + 1.f);
                float r1 = __builtin_amdgcn_rcpf(__expf(2.f * (x.y + g.y)) + 1.f);
                float r2 = __builtin_amdgcn_rcpf(__expf(2.f * (x.z + g.z)) + 1.f);
                float r3 = __builtin_amdgcn_rcpf(__expf(2.f * (x.w + g.w)) + 1.f);
                s = fmaf(1.f - 2.f * r0, w.x, s);
                s = fmaf(1.f - 2.f * r1, w.y, s);
                s = fmaf(1.f - 2.f * r2, w.z, s);
                s = fmaf(1.f - 2.f * r3, w.w, s);
            }
            {
                float x = cvl[lane * 52 + 48] + cgl[tl * 52 + 48];
                float r0 = __builtin_amdgcn_rcpf(__expf(2.f * x) + 1.f);
                s = fmaf(1.f - 2.f * r0, whl[48], s);
            }
            z = s;
        }
        float m = z;
        for (int off = 32; off; off >>= 1) m = fmaxf(m, __shfl_xor(m, off));
        float p = (lane < 49) ? __expf(z - m) : 0.f;
        float sum = p;
        for (int off = 32; off; off >>= 1) sum += __shfl_xor(sum, off);
        const float val = p * __builtin_amdgcn_rcpf(sum);  // 0 for lane>=49

        const size_t grow = (size_t)b * 256 + t0 + tl;
        if (lane < 49) alpha[grow * 49 + lane] = val;
        const int pos = (((lane >> 3) ^ (tl & 7)) << 3) | (lane & 7);
        Al[tl * 64 + pos] = (short)f2bf_bits(val);
    }
    __syncthreads();  // Al valid; the only phase-2 barrier

    // ---- phase 2: c_t = alpha @ V^T; wave owns h stripe [wave*256, +256) ----
    bf16x8 af[2];
#pragma unroll
    for (int kc = 0; kc < 2; ++kc)
        af[kc] = *(const bf16x8*)(Al + l16 * 64 + (((kc << 2) + quad) ^ (l16 & 7)) * 8);

    const int hb = wave * 256;
    const unsigned short* vb = vT + ((size_t)b * 1024 + hb) * 64;

    floatx4 acc[16] = {};
#pragma unroll
    for (int ns = 0; ns < 16; ++ns) {
        const int row = ns * 16 + l16;  // hb%256==0 -> row&7 == global h&7
        const unsigned short* vrow = vb + (size_t)row * 64;
        bf16x8 b0 = *(const bf16x8*)(vrow + ((quad ^ (row & 7)) * 8));
        bf16x8 b1 = *(const bf16x8*)(vrow + (((4 + quad) ^ (row & 7)) * 8));
        acc[ns] = __builtin_amdgcn_mfma_f32_16x16x32_bf16(af[0], b0, acc[ns], 0, 0, 0);
        acc[ns] = __builtin_amdgcn_mfma_f32_16x16x32_bf16(af[1], b1, acc[ns], 0, 0, 0);
    }

#pragma unroll
    for (int ns = 0; ns < 16; ++ns) {
        const int h = hb + ns * 16 + l16;
#pragma unroll
        for (int r = 0; r < 4; ++r) {
            const int t = t0 + quad * 4 + r;
            C[((size_t)b * 256 + t) * 1024 + h] = acc[ns][r];
        }
    }
}

extern "C" void kernel_launch(void* const* d_in, const int* in_sizes, int n_in,
                              void* d_out, int out_size, void* d_ws, size_t ws_size,
                              hipStream_t stream) {
    const float* V   = (const float*)d_in[0];
    const float* h_t = (const float*)d_in[1];
    const float* Wv  = (const float*)d_in[2];
    const float* Wg  = (const float*)d_in[3];
    const float* Wh  = (const float*)d_in[4];

    float* c_t   = (float*)d_out;
    float* alpha = (float*)d_out + 16777216;

    float* cv = (float*)d_ws;                                       // 153664 f
    float* cg = cv + 153664;                                        // 802816 f
    unsigned short* vT = (unsigned short*)((char*)d_ws + 3825920);  // 64*1024*64

    gemm_mfma_tr<<<610 + 512, 256, 0, stream>>>(V, h_t, Wv, Wg, cv, cg, vT);
    zsoftmax_ct<<<1024, 256, 0, stream>>>(cv, cg, Wh, vT, alpha, c_t);
}

// Round 4
// 170.427 us; speedup vs baseline: 1.0679x; 1.0210x over previous
//
#include <hip/hip_runtime.h>
#include <hip/hip_bf16.h>
#include <math.h>
#include <stdint.h>

// Shapes: B=64, T=256, R=49, H=1024
// out = [c_t (B*T*H fp32)] ++ [alpha (B*T*R fp32)]
// ws  = [cv fp32 3136x49][cg fp32 16384x49][vT bf16 64x1024x64 swizzled] (~12.2 MB)
//
// Round 4: isolate round-3's failure. zsoftmax_ct = byte-exact round 2.
// GEMM M-tile 64 retried with staging rebuilt from round-2 verbatim patterns:
// W-staging identical to round 2 (wrow=tid>>2 covers 64 rows); A-staging is
// round-2's one-octet pattern applied to rows arow and arow+32 (same XOR since
// (arow+32)&7 == arow&7). MFMA: 8 per barrier-pair per wave (was 4).

typedef __attribute__((ext_vector_type(8))) short bf16x8;
typedef __attribute__((ext_vector_type(4))) float floatx4;

static __device__ __forceinline__ bf16x8 pack8(float4 a, float4 b) {
    union { __hip_bfloat162 h[4]; bf16x8 v; } u;
    u.h[0] = __float22bfloat162_rn(make_float2(a.x, a.y));
    u.h[1] = __float22bfloat162_rn(make_float2(a.z, a.w));
    u.h[2] = __float22bfloat162_rn(make_float2(b.x, b.y));
    u.h[3] = __float22bfloat162_rn(make_float2(b.z, b.w));
    return u.v;
}

static __device__ __forceinline__ unsigned short f2bf_bits(float f) {
    union { __hip_bfloat16 h; unsigned short u; } c;
    c.h = __float2bfloat16(f);
    return c.u;
}

// Blocks 0..48: cv = V.Wv^T (M-tile 64); 49..304: cg = h_t.Wg^T (M-tile 64);
// 305..816: transpose V -> vT[b][h][r(pad 64)] bf16, octet-swizzled rows.
__global__ __launch_bounds__(256) void gemm_mfma_tr(const float* __restrict__ Av,
                                                    const float* __restrict__ Ag,
                                                    const float* __restrict__ Wv,
                                                    const float* __restrict__ Wg,
                                                    float* __restrict__ Cv,
                                                    float* __restrict__ Cg,
                                                    unsigned short* __restrict__ vT) {
    __shared__ __align__(16) char smem[49 * 132 * 4];  // 25872 B, union
    const int bid = blockIdx.x;
    const int tid = threadIdx.x;

    if (bid >= 305) {
        // ---- V transpose: one (b, 128-h slice) per block ----
        float* Ts = (float*)smem;  // [49][132]
        const int tb = bid - 305;
        const int b = tb >> 3;
        const int h0 = (tb & 7) * 128;
        for (int i = tid; i < 49 * 32; i += 256) {
            const int r = i >> 5, hq = i & 31;
            *(float4*)(Ts + r * 132 + hq * 4) =
                *(const float4*)(Av + ((size_t)b * 49 + r) * 1024 + h0 + hq * 4);
        }
        __syncthreads();
        const int h = tid & 127;
        const int half = tid >> 7;  // 0: r 0..31 (octets 0..3), 1: r 32..63 (4..7)
        float f[32];
#pragma unroll
        for (int j = 0; j < 32; ++j) {
            const int r = half * 32 + j;
            f[j] = (r < 49) ? Ts[r * 132 + h] : 0.f;
        }
        const size_t rowbase = ((size_t)b * 1024 + h0 + h) * 64;
#pragma unroll
        for (int o2 = 0; o2 < 4; ++o2) {
            const int o = half * 4 + o2;
            bf16x8 v = pack8(make_float4(f[o2*8+0], f[o2*8+1], f[o2*8+2], f[o2*8+3]),
                             make_float4(f[o2*8+4], f[o2*8+5], f[o2*8+6], f[o2*8+7]));
            *(bf16x8*)(vT + rowbase + (size_t)((o ^ (h & 7)) * 8)) = v;
        }
        return;
    }

    // ---- GEMM C[m][n] = sum_k A[m][k]*W[n][k], M-tile 64, K=1024, N=49->64 ----
    short* As = (short*)smem;           // [64][64] bf16, octet-swizzled
    short* Ws = (short*)(smem + 8192);  // [64][64]
    const float* A; const float* W; float* C; int m0;
    if (bid < 49) { A = Av; W = Wv; C = Cv; m0 = bid * 64; }
    else          { A = Ag; W = Wg; C = Cg; m0 = (bid - 49) * 64; }

    const int wave = tid >> 6, lane = tid & 63;
    const int quad = lane >> 4, l16 = lane & 15;

    floatx4 acc[4] = {};  // wave owns m [wave*16,+16) x n [0,64)

    // A staging: round-2 pattern, applied to rows arow and arow+32.
    const int arow = tid >> 3, ag = tid & 7;
    const float* aptr = A + (size_t)(m0 + arow) * 1024 + ag * 8;
    const float* bptr = aptr + 32 * 1024;  // row arow+32, same octet
    // W staging: byte-identical round-2 code.
    const int wrow = tid >> 2, wq = tid & 3;
    const bool wvalid = wrow < 49;
    const float* wptr = W + (size_t)wrow * 1024 + wq * 16;

    float4 a0 = *(const float4*)(aptr);
    float4 a1 = *(const float4*)(aptr + 4);
    float4 b0 = *(const float4*)(bptr);
    float4 b1 = *(const float4*)(bptr + 4);
    float4 w0 = make_float4(0.f,0.f,0.f,0.f), w1 = w0, w2 = w0, w3 = w0;
    if (wvalid) {
        w0 = *(const float4*)(wptr);
        w1 = *(const float4*)(wptr + 4);
        w2 = *(const float4*)(wptr + 8);
        w3 = *(const float4*)(wptr + 12);
    }

    for (int kc = 0; kc < 1024; kc += 64) {
        __syncthreads();
        *(bf16x8*)(As + arow * 64 + (ag ^ (arow & 7)) * 8)        = pack8(a0, a1);
        *(bf16x8*)(As + (arow + 32) * 64 + (ag ^ (arow & 7)) * 8) = pack8(b0, b1);
        *(bf16x8*)(Ws + wrow * 64 + ((wq * 2) ^ (wrow & 7)) * 8)     = pack8(w0, w1);
        *(bf16x8*)(Ws + wrow * 64 + ((wq * 2 + 1) ^ (wrow & 7)) * 8) = pack8(w2, w3);
        __syncthreads();
        if (kc < 960) {  // prefetch next tile; latency hides under MFMA below
            a0 = *(const float4*)(aptr + kc + 64);
            a1 = *(const float4*)(aptr + kc + 68);
            b0 = *(const float4*)(bptr + kc + 64);
            b1 = *(const float4*)(bptr + kc + 68);
            if (wvalid) {
                w0 = *(const float4*)(wptr + kc + 64);
                w1 = *(const float4*)(wptr + kc + 68);
                w2 = *(const float4*)(wptr + kc + 72);
                w3 = *(const float4*)(wptr + kc + 76);
            }
        }
#pragma unroll
        for (int s = 0; s < 2; ++s) {
            const int am = wave * 16 + l16;
            bf16x8 af = *(const bf16x8*)(As + am * 64 + (((s << 2) + quad) ^ (am & 7)) * 8);
#pragma unroll
            for (int nt = 0; nt < 4; ++nt) {
                const int wn = nt * 16 + l16;
                bf16x8 bf = *(const bf16x8*)(Ws + wn * 64 + (((s << 2) + quad) ^ (wn & 7)) * 8);
                acc[nt] = __builtin_amdgcn_mfma_f32_16x16x32_bf16(af, bf, acc[nt], 0, 0, 0);
            }
        }
    }

#pragma unroll
    for (int nt = 0; nt < 4; ++nt) {
        const int n = nt * 16 + l16;
        if (n < 49) {
#pragma unroll
            for (int r = 0; r < 4; ++r) {
                const int m = m0 + wave * 16 + quad * 4 + r;
                C[(size_t)m * 49 + n] = acc[nt][r];
            }
        }
    }
}

// Fused: z[b,t,r] = sum_k tanh(cv[b,r,k]+cg[b,t,k])*Wh[k]; alpha=softmax_r(z);
// c_t[b,t,h] = sum_r alpha*V via bf16 MFMA with B-fragments read straight
// from global vT (L2-resident). Block = (b, 16-row t-tile), grid 64*16=1024.
// XCD-chunked bid swizzle: contiguous 128-block chunks per XCD.
// (byte-exact round-2 version)
__global__ __launch_bounds__(256) void zsoftmax_ct(const float* __restrict__ cv,
                                                   const float* __restrict__ cg,
                                                   const float* __restrict__ Wh,
                                                   const unsigned short* __restrict__ vT,
                                                   float* __restrict__ alpha,
                                                   float* __restrict__ C) {
    const int bid = blockIdx.x;
    const int orig = (bid & 7) * 128 + (bid >> 3);
    const int b = orig >> 4;
    const int t0 = (orig & 15) * 16;

    __shared__ __align__(16) short Al[16 * 64];  // [t][r] bf16, swizzled
    __shared__ __align__(16) float cvl[49 * 52];
    __shared__ __align__(16) float cgl[16 * 52];
    __shared__ __align__(16) float whl[52];

    const int tid = threadIdx.x;
    for (int i = tid; i < 49 * 49; i += 256) {
        int r = i / 49, k = i - r * 49;
        cvl[r * 52 + k] = cv[(size_t)b * 2401 + i];
    }
    for (int i = tid; i < 16 * 49; i += 256) {
        int t = i / 49, k = i - t * 49;
        cgl[t * 52 + k] = cg[((size_t)b * 256 + t0) * 49 + i];
    }
    if (tid < 52) whl[tid] = (tid < 49) ? Wh[tid] : 0.f;
    __syncthreads();

    const int wave = tid >> 6;
    const int lane = tid & 63;
    const int quad = lane >> 4, l16 = lane & 15;
    const float4* cvr = (const float4*)(cvl + lane * 52);
    const float4* wh4 = (const float4*)whl;

    // ---- phase 1: z + softmax; alpha -> global fp32 + LDS bf16 (swizzled) ----
#pragma unroll
    for (int i = 0; i < 4; ++i) {
        const int tl = wave * 4 + i;
        float z = -INFINITY;
        if (lane < 49) {
            const float4* cgr = (const float4*)(cgl + tl * 52);
            float s = 0.f;
#pragma unroll 4
            for (int kk = 0; kk < 12; ++kk) {
                float4 x = cvr[kk], g = cgr[kk], w = wh4[kk];
                float r0 = __builtin_amdgcn_rcpf(__expf(2.f * (x.x + g.x)) + 1.f);
                float r1 = __builtin_amdgcn_rcpf(__expf(2.f * (x.y + g.y)) + 1.f);
                float r2 = __builtin_amdgcn_rcpf(__expf(2.f * (x.z + g.z)) + 1.f);
                float r3 = __builtin_amdgcn_rcpf(__expf(2.f * (x.w + g.w)) + 1.f);
                s = fmaf(1.f - 2.f * r0, w.x, s);
                s = fmaf(1.f - 2.f * r1, w.y, s);
                s = fmaf(1.f - 2.f * r2, w.z, s);
                s = fmaf(1.f - 2.f * r3, w.w, s);
            }
            {
                float x = cvl[lane * 52 + 48] + cgl[tl * 52 + 48];
                float r0 = __builtin_amdgcn_rcpf(__expf(2.f * x) + 1.f);
                s = fmaf(1.f - 2.f * r0, whl[48], s);
            }
            z = s;
        }
        float m = z;
        for (int off = 32; off; off >>= 1) m = fmaxf(m, __shfl_xor(m, off));
        float p = (lane < 49) ? __expf(z - m) : 0.f;
        float sum = p;
        for (int off = 32; off; off >>= 1) sum += __shfl_xor(sum, off);
        const float val = p * __builtin_amdgcn_rcpf(sum);  // 0 for lane>=49

        const size_t grow = (size_t)b * 256 + t0 + tl;
        if (lane < 49) alpha[grow * 49 + lane] = val;
        const int pos = (((lane >> 3) ^ (tl & 7)) << 3) | (lane & 7);
        Al[tl * 64 + pos] = (short)f2bf_bits(val);
    }
    __syncthreads();  // Al valid; the only phase-2 barrier

    // ---- phase 2: c_t = alpha @ V^T; wave owns h stripe [wave*256, +256) ----
    bf16x8 af[2];
#pragma unroll
    for (int kc = 0; kc < 2; ++kc)
        af[kc] = *(const bf16x8*)(Al + l16 * 64 + (((kc << 2) + quad) ^ (l16 & 7)) * 8);

    const int hb = wave * 256;
    const unsigned short* vb = vT + ((size_t)b * 1024 + hb) * 64;

    floatx4 acc[16] = {};
#pragma unroll
    for (int ns = 0; ns < 16; ++ns) {
        const int row = ns * 16 + l16;  // hb%256==0 -> row&7 == global h&7
        const unsigned short* vrow = vb + (size_t)row * 64;
        bf16x8 b0 = *(const bf16x8*)(vrow + ((quad ^ (row & 7)) * 8));
        bf16x8 b1 = *(const bf16x8*)(vrow + (((4 + quad) ^ (row & 7)) * 8));
        acc[ns] = __builtin_amdgcn_mfma_f32_16x16x32_bf16(af[0], b0, acc[ns], 0, 0, 0);
        acc[ns] = __builtin_amdgcn_mfma_f32_16x16x32_bf16(af[1], b1, acc[ns], 0, 0, 0);
    }

#pragma unroll
    for (int ns = 0; ns < 16; ++ns) {
        const int h = hb + ns * 16 + l16;
#pragma unroll
        for (int r = 0; r < 4; ++r) {
            const int t = t0 + quad * 4 + r;
            C[((size_t)b * 256 + t) * 1024 + h] = acc[ns][r];
        }
    }
}

extern "C" void kernel_launch(void* const* d_in, const int* in_sizes, int n_in,
                              void* d_out, int out_size, void* d_ws, size_t ws_size,
                              hipStream_t stream) {
    const float* V   = (const float*)d_in[0];
    const float* h_t = (const float*)d_in[1];
    const float* Wv  = (const float*)d_in[2];
    const float* Wg  = (const float*)d_in[3];
    const float* Wh  = (const float*)d_in[4];

    float* c_t   = (float*)d_out;
    float* alpha = (float*)d_out + 16777216;

    float* cv = (float*)d_ws;                                       // 153664 f
    float* cg = cv + 153664;                                        // 802816 f
    unsigned short* vT = (unsigned short*)((char*)d_ws + 3825920);  // 64*1024*64

    gemm_mfma_tr<<<305 + 512, 256, 0, stream>>>(V, h_t, Wv, Wg, cv, cg, vT);
    zsoftmax_ct<<<1024, 256, 0, stream>>>(cv, cg, Wh, vT, alpha, c_t);
}

// Round 5
// 160.181 us; speedup vs baseline: 1.1362x; 1.0640x over previous
//
#include <hip/hip_runtime.h>
#include <hip/hip_bf16.h>
#include <math.h>
#include <stdint.h>

// Shapes: B=64, T=256, R=49, H=1024
// out = [c_t (B*T*H fp32)] ++ [alpha (B*T*R fp32)]
// ws  = [cv fp32 3136x49][cg fp32 16384x49][vT bf16 64x1024x64 swizzled] (~12.2 MB)
//
// Round 5: zsoftmax_ct re-structured for occupancy: 512-thread blocks (8 waves),
// 2 t-rows/wave in phase 1, 128-h stripe (acc[8]) per wave in phase 2,
// __launch_bounds__(512,8) to cap VGPR at 64 -> 32 waves/CU (was 68 VGPR/16 waves).
// GEMM byte-identical to round 4 (verified).

typedef __attribute__((ext_vector_type(8))) short bf16x8;
typedef __attribute__((ext_vector_type(4))) float floatx4;

static __device__ __forceinline__ bf16x8 pack8(float4 a, float4 b) {
    union { __hip_bfloat162 h[4]; bf16x8 v; } u;
    u.h[0] = __float22bfloat162_rn(make_float2(a.x, a.y));
    u.h[1] = __float22bfloat162_rn(make_float2(a.z, a.w));
    u.h[2] = __float22bfloat162_rn(make_float2(b.x, b.y));
    u.h[3] = __float22bfloat162_rn(make_float2(b.z, b.w));
    return u.v;
}

static __device__ __forceinline__ unsigned short f2bf_bits(float f) {
    union { __hip_bfloat16 h; unsigned short u; } c;
    c.h = __float2bfloat16(f);
    return c.u;
}

// Blocks 0..48: cv = V.Wv^T (M-tile 64); 49..304: cg = h_t.Wg^T (M-tile 64);
// 305..816: transpose V -> vT[b][h][r(pad 64)] bf16, octet-swizzled rows.
__global__ __launch_bounds__(256) void gemm_mfma_tr(const float* __restrict__ Av,
                                                    const float* __restrict__ Ag,
                                                    const float* __restrict__ Wv,
                                                    const float* __restrict__ Wg,
                                                    float* __restrict__ Cv,
                                                    float* __restrict__ Cg,
                                                    unsigned short* __restrict__ vT) {
    __shared__ __align__(16) char smem[49 * 132 * 4];  // 25872 B, union
    const int bid = blockIdx.x;
    const int tid = threadIdx.x;

    if (bid >= 305) {
        // ---- V transpose: one (b, 128-h slice) per block ----
        float* Ts = (float*)smem;  // [49][132]
        const int tb = bid - 305;
        const int b = tb >> 3;
        const int h0 = (tb & 7) * 128;
        for (int i = tid; i < 49 * 32; i += 256) {
            const int r = i >> 5, hq = i & 31;
            *(float4*)(Ts + r * 132 + hq * 4) =
                *(const float4*)(Av + ((size_t)b * 49 + r) * 1024 + h0 + hq * 4);
        }
        __syncthreads();
        const int h = tid & 127;
        const int half = tid >> 7;  // 0: r 0..31 (octets 0..3), 1: r 32..63 (4..7)
        float f[32];
#pragma unroll
        for (int j = 0; j < 32; ++j) {
            const int r = half * 32 + j;
            f[j] = (r < 49) ? Ts[r * 132 + h] : 0.f;
        }
        const size_t rowbase = ((size_t)b * 1024 + h0 + h) * 64;
#pragma unroll
        for (int o2 = 0; o2 < 4; ++o2) {
            const int o = half * 4 + o2;
            bf16x8 v = pack8(make_float4(f[o2*8+0], f[o2*8+1], f[o2*8+2], f[o2*8+3]),
                             make_float4(f[o2*8+4], f[o2*8+5], f[o2*8+6], f[o2*8+7]));
            *(bf16x8*)(vT + rowbase + (size_t)((o ^ (h & 7)) * 8)) = v;
        }
        return;
    }

    // ---- GEMM C[m][n] = sum_k A[m][k]*W[n][k], M-tile 64, K=1024, N=49->64 ----
    short* As = (short*)smem;           // [64][64] bf16, octet-swizzled
    short* Ws = (short*)(smem + 8192);  // [64][64]
    const float* A; const float* W; float* C; int m0;
    if (bid < 49) { A = Av; W = Wv; C = Cv; m0 = bid * 64; }
    else          { A = Ag; W = Wg; C = Cg; m0 = (bid - 49) * 64; }

    const int wave = tid >> 6, lane = tid & 63;
    const int quad = lane >> 4, l16 = lane & 15;

    floatx4 acc[4] = {};  // wave owns m [wave*16,+16) x n [0,64)

    // A staging: round-2 pattern, applied to rows arow and arow+32.
    const int arow = tid >> 3, ag = tid & 7;
    const float* aptr = A + (size_t)(m0 + arow) * 1024 + ag * 8;
    const float* bptr = aptr + 32 * 1024;  // row arow+32, same octet
    // W staging: byte-identical round-2 code.
    const int wrow = tid >> 2, wq = tid & 3;
    const bool wvalid = wrow < 49;
    const float* wptr = W + (size_t)wrow * 1024 + wq * 16;

    float4 a0 = *(const float4*)(aptr);
    float4 a1 = *(const float4*)(aptr + 4);
    float4 b0 = *(const float4*)(bptr);
    float4 b1 = *(const float4*)(bptr + 4);
    float4 w0 = make_float4(0.f,0.f,0.f,0.f), w1 = w0, w2 = w0, w3 = w0;
    if (wvalid) {
        w0 = *(const float4*)(wptr);
        w1 = *(const float4*)(wptr + 4);
        w2 = *(const float4*)(wptr + 8);
        w3 = *(const float4*)(wptr + 12);
    }

    for (int kc = 0; kc < 1024; kc += 64) {
        __syncthreads();
        *(bf16x8*)(As + arow * 64 + (ag ^ (arow & 7)) * 8)        = pack8(a0, a1);
        *(bf16x8*)(As + (arow + 32) * 64 + (ag ^ (arow & 7)) * 8) = pack8(b0, b1);
        *(bf16x8*)(Ws + wrow * 64 + ((wq * 2) ^ (wrow & 7)) * 8)     = pack8(w0, w1);
        *(bf16x8*)(Ws + wrow * 64 + ((wq * 2 + 1) ^ (wrow & 7)) * 8) = pack8(w2, w3);
        __syncthreads();
        if (kc < 960) {  // prefetch next tile; latency hides under MFMA below
            a0 = *(const float4*)(aptr + kc + 64);
            a1 = *(const float4*)(aptr + kc + 68);
            b0 = *(const float4*)(bptr + kc + 64);
            b1 = *(const float4*)(bptr + kc + 68);
            if (wvalid) {
                w0 = *(const float4*)(wptr + kc + 64);
                w1 = *(const float4*)(wptr + kc + 68);
                w2 = *(const float4*)(wptr + kc + 72);
                w3 = *(const float4*)(wptr + kc + 76);
            }
        }
#pragma unroll
        for (int s = 0; s < 2; ++s) {
            const int am = wave * 16 + l16;
            bf16x8 af = *(const bf16x8*)(As + am * 64 + (((s << 2) + quad) ^ (am & 7)) * 8);
#pragma unroll
            for (int nt = 0; nt < 4; ++nt) {
                const int wn = nt * 16 + l16;
                bf16x8 bf = *(const bf16x8*)(Ws + wn * 64 + (((s << 2) + quad) ^ (wn & 7)) * 8);
                acc[nt] = __builtin_amdgcn_mfma_f32_16x16x32_bf16(af, bf, acc[nt], 0, 0, 0);
            }
        }
    }

#pragma unroll
    for (int nt = 0; nt < 4; ++nt) {
        const int n = nt * 16 + l16;
        if (n < 49) {
#pragma unroll
            for (int r = 0; r < 4; ++r) {
                const int m = m0 + wave * 16 + quad * 4 + r;
                C[(size_t)m * 49 + n] = acc[nt][r];
            }
        }
    }
}

// Fused: z[b,t,r] = sum_k tanh(cv[b,r,k]+cg[b,t,k])*Wh[k]; alpha=softmax_r(z);
// c_t[b,t,h] = sum_r alpha*V via bf16 MFMA with B-fragments read straight
// from global vT (L2-resident). Block = (b, 16-row t-tile), 512 threads/8 waves,
// grid 64*16=1024. XCD-chunked bid swizzle: contiguous 128-block chunks per XCD.
__global__ __launch_bounds__(512, 8) void zsoftmax_ct(const float* __restrict__ cv,
                                                      const float* __restrict__ cg,
                                                      const float* __restrict__ Wh,
                                                      const unsigned short* __restrict__ vT,
                                                      float* __restrict__ alpha,
                                                      float* __restrict__ C) {
    const int bid = blockIdx.x;
    const int orig = (bid & 7) * 128 + (bid >> 3);
    const int b = orig >> 4;
    const int t0 = (orig & 15) * 16;

    __shared__ __align__(16) short Al[16 * 64];  // [t][r] bf16, swizzled
    __shared__ __align__(16) float cvl[49 * 52];
    __shared__ __align__(16) float cgl[16 * 52];
    __shared__ __align__(16) float whl[52];

    const int tid = threadIdx.x;
    for (int i = tid; i < 49 * 49; i += 512) {
        int r = i / 49, k = i - r * 49;
        cvl[r * 52 + k] = cv[(size_t)b * 2401 + i];
    }
    for (int i = tid; i < 16 * 49; i += 512) {
        int t = i / 49, k = i - t * 49;
        cgl[t * 52 + k] = cg[((size_t)b * 256 + t0) * 49 + i];
    }
    if (tid < 52) whl[tid] = (tid < 49) ? Wh[tid] : 0.f;
    __syncthreads();

    const int wave = tid >> 6;
    const int lane = tid & 63;
    const int quad = lane >> 4, l16 = lane & 15;
    const float4* cvr = (const float4*)(cvl + lane * 52);
    const float4* wh4 = (const float4*)whl;

    // ---- phase 1: z + softmax; alpha -> global fp32 + LDS bf16 (swizzled) ----
#pragma unroll
    for (int i = 0; i < 2; ++i) {
        const int tl = wave * 2 + i;
        float z = -INFINITY;
        if (lane < 49) {
            const float4* cgr = (const float4*)(cgl + tl * 52);
            float s = 0.f;
#pragma unroll 4
            for (int kk = 0; kk < 12; ++kk) {
                float4 x = cvr[kk], g = cgr[kk], w = wh4[kk];
                float r0 = __builtin_amdgcn_rcpf(__expf(2.f * (x.x + g.x)) + 1.f);
                float r1 = __builtin_amdgcn_rcpf(__expf(2.f * (x.y + g.y)) + 1.f);
                float r2 = __builtin_amdgcn_rcpf(__expf(2.f * (x.z + g.z)) + 1.f);
                float r3 = __builtin_amdgcn_rcpf(__expf(2.f * (x.w + g.w)) + 1.f);
                s = fmaf(1.f - 2.f * r0, w.x, s);
                s = fmaf(1.f - 2.f * r1, w.y, s);
                s = fmaf(1.f - 2.f * r2, w.z, s);
                s = fmaf(1.f - 2.f * r3, w.w, s);
            }
            {
                float x = cvl[lane * 52 + 48] + cgl[tl * 52 + 48];
                float r0 = __builtin_amdgcn_rcpf(__expf(2.f * x) + 1.f);
                s = fmaf(1.f - 2.f * r0, whl[48], s);
            }
            z = s;
        }
        float m = z;
        for (int off = 32; off; off >>= 1) m = fmaxf(m, __shfl_xor(m, off));
        float p = (lane < 49) ? __expf(z - m) : 0.f;
        float sum = p;
        for (int off = 32; off; off >>= 1) sum += __shfl_xor(sum, off);
        const float val = p * __builtin_amdgcn_rcpf(sum);  // 0 for lane>=49

        const size_t grow = (size_t)b * 256 + t0 + tl;
        if (lane < 49) alpha[grow * 49 + lane] = val;
        const int pos = (((lane >> 3) ^ (tl & 7)) << 3) | (lane & 7);
        Al[tl * 64 + pos] = (short)f2bf_bits(val);
    }
    __syncthreads();  // Al valid; the only phase-2 barrier

    // ---- phase 2: c_t = alpha @ V^T; wave owns h stripe [wave*128, +128) ----
    bf16x8 af[2];
#pragma unroll
    for (int kc = 0; kc < 2; ++kc)
        af[kc] = *(const bf16x8*)(Al + l16 * 64 + (((kc << 2) + quad) ^ (l16 & 7)) * 8);

    const int hb = wave * 128;
    const unsigned short* vb = vT + ((size_t)b * 1024 + hb) * 64;

    floatx4 acc[8] = {};
#pragma unroll
    for (int ns = 0; ns < 8; ++ns) {
        const int row = ns * 16 + l16;  // hb%8==0 -> (hb+row)&7 == row&7
        const unsigned short* vrow = vb + (size_t)row * 64;
        bf16x8 b0 = *(const bf16x8*)(vrow + ((quad ^ (row & 7)) * 8));
        bf16x8 b1 = *(const bf16x8*)(vrow + (((4 + quad) ^ (row & 7)) * 8));
        acc[ns] = __builtin_amdgcn_mfma_f32_16x16x32_bf16(af[0], b0, acc[ns], 0, 0, 0);
        acc[ns] = __builtin_amdgcn_mfma_f32_16x16x32_bf16(af[1], b1, acc[ns], 0, 0, 0);
    }

#pragma unroll
    for (int ns = 0; ns < 8; ++ns) {
        const int h = hb + ns * 16 + l16;
#pragma unroll
        for (int r = 0; r < 4; ++r) {
            const int t = t0 + quad * 4 + r;
            C[((size_t)b * 256 + t) * 1024 + h] = acc[ns][r];
        }
    }
}

extern "C" void kernel_launch(void* const* d_in, const int* in_sizes, int n_in,
                              void* d_out, int out_size, void* d_ws, size_t ws_size,
                              hipStream_t stream) {
    const float* V   = (const float*)d_in[0];
    const float* h_t = (const float*)d_in[1];
    const float* Wv  = (const float*)d_in[2];
    const float* Wg  = (const float*)d_in[3];
    const float* Wh  = (const float*)d_in[4];

    float* c_t   = (float*)d_out;
    float* alpha = (float*)d_out + 16777216;

    float* cv = (float*)d_ws;                                       // 153664 f
    float* cg = cv + 153664;                                        // 802816 f
    unsigned short* vT = (unsigned short*)((char*)d_ws + 3825920);  // 64*1024*64

    gemm_mfma_tr<<<305 + 512, 256, 0, stream>>>(V, h_t, Wv, Wg, cv, cg, vT);
    zsoftmax_ct<<<1024, 512, 0, stream>>>(cv, cg, Wh, vT, alpha, c_t);
}